// Round 1
// baseline (5506.741 us; speedup 1.0000x reference)
//
#include <hip/hip_runtime.h>

#define D 128
#define LN_EPS 1e-5f

// Scatter-add: out[dst] += val * h[src] * w   (32 lanes/edge, float4/lane)
__global__ void gat_scatter_kernel(const float* __restrict__ h,
                                   const int* __restrict__ src,
                                   const int* __restrict__ dst,
                                   const float* __restrict__ val,
                                   const float* __restrict__ w,
                                   float* __restrict__ out, int E) {
    long long t = (long long)blockIdx.x * blockDim.x + threadIdx.x;
    int e = (int)(t >> 5);      // 32 threads per edge
    int lane = (int)(t & 31);   // each lane does a float4 chunk
    if (e >= E) return;

    int s = src[e];
    int dv = dst[e];
    float v = val[e];

    const float4* hp = (const float4*)(h + (size_t)s * D);
    float4 hv = hp[lane];
    float4 wv = ((const float4*)w)[lane];

    float* op = out + (size_t)dv * D + lane * 4;
    atomicAdd(op + 0, v * hv.x * wv.x);
    atomicAdd(op + 1, v * hv.y * wv.y);
    atomicAdd(op + 2, v * hv.z * wv.z);
    atomicAdd(op + 3, v * hv.w * wv.w);
}

// LayerNorm over D=128, one wave64 per node, float2 per lane. Optional ReLU.
__global__ void ln_kernel(const float* __restrict__ in,
                          const float* __restrict__ g,
                          const float* __restrict__ b,
                          float* __restrict__ out, int N, int do_relu) {
    int wave_in_block = threadIdx.x >> 6;
    int node = blockIdx.x * (blockDim.x >> 6) + wave_in_block;
    int lane = threadIdx.x & 63;
    if (node >= N) return;

    float2 x = ((const float2*)(in + (size_t)node * D))[lane];

    float sum = x.x + x.y;
    #pragma unroll
    for (int off = 32; off > 0; off >>= 1) sum += __shfl_down(sum, off, 64);
    sum = __shfl(sum, 0, 64);
    float mu = sum * (1.0f / D);

    float dx = x.x - mu, dy = x.y - mu;
    float sq = dx * dx + dy * dy;
    #pragma unroll
    for (int off = 32; off > 0; off >>= 1) sq += __shfl_down(sq, off, 64);
    sq = __shfl(sq, 0, 64);
    float rstd = rsqrtf(sq * (1.0f / D) + LN_EPS);

    float2 gv = ((const float2*)g)[lane];
    float2 bv = ((const float2*)b)[lane];
    float2 o;
    o.x = dx * rstd * gv.x + bv.x;
    o.y = dy * rstd * gv.y + bv.y;
    if (do_relu) { o.x = fmaxf(o.x, 0.0f); o.y = fmaxf(o.y, 0.0f); }
    ((float2*)(out + (size_t)node * D))[lane] = o;
}

extern "C" void kernel_launch(void* const* d_in, const int* in_sizes, int n_in,
                              void* d_out, int out_size, void* d_ws, size_t ws_size,
                              hipStream_t stream) {
    const float* x    = (const float*)d_in[0];
    const int*   esrc = (const int*)d_in[1];
    const int*   edst = (const int*)d_in[2];
    const float* eval_= (const float*)d_in[3];
    const float* w1   = (const float*)d_in[4];
    const float* w2   = (const float*)d_in[5];
    const float* g1   = (const float*)d_in[6];
    const float* b1   = (const float*)d_in[7];
    const float* g2   = (const float*)d_in[8];
    const float* b2   = (const float*)d_in[9];
    float* out = (float*)d_out;

    const int N = in_sizes[0] / D;   // 100000
    const int E = in_sizes[1];       // 1600000

    float* bufA = (float*)d_ws;                    // accumulator
    float* bufB = bufA + (size_t)N * D;            // h after LN+ReLU
    const size_t node_bytes = (size_t)N * D * sizeof(float);

    const int scat_threads = 256;
    const long long scat_total = (long long)E * 32;
    const int scat_blocks = (int)((scat_total + scat_threads - 1) / scat_threads);
    const int ln_blocks = (N + 3) / 4;   // 4 waves (nodes) per 256-thread block

    // Layer 1
    hipMemsetAsync(bufA, 0, node_bytes, stream);
    gat_scatter_kernel<<<scat_blocks, scat_threads, 0, stream>>>(
        x, esrc, edst, eval_, w1, bufA, E);
    ln_kernel<<<ln_blocks, 256, 0, stream>>>(bufA, g1, b1, bufB, N, 1);

    // Layer 2
    hipMemsetAsync(bufA, 0, node_bytes, stream);
    gat_scatter_kernel<<<scat_blocks, scat_threads, 0, stream>>>(
        bufB, esrc, edst, eval_, w2, bufA, E);
    ln_kernel<<<ln_blocks, 256, 0, stream>>>(bufA, g2, b2, out, N, 0);
}

// Round 2
// 591.249 us; speedup vs baseline: 9.3137x; 9.3137x over previous
//
#include <hip/hip_runtime.h>

#define D 128
#define LN_EPS 1e-5f
#define SCAN_CHUNK 256

// ---------- CSR build ----------

__global__ void hist_kernel(const int* __restrict__ dst, int* __restrict__ deg, int E) {
    int e = blockIdx.x * blockDim.x + threadIdx.x;
    if (e < E) atomicAdd(&deg[dst[e]], 1);
}

// Per-block exclusive scan of deg chunk -> offsets (block-local), block total -> blockSums
__global__ void scan_local_kernel(const int* __restrict__ deg, int* __restrict__ offsets,
                                  int* __restrict__ blockSums, int N) {
    __shared__ int sm[SCAN_CHUNK];
    int i = blockIdx.x * SCAN_CHUNK + threadIdx.x;
    int v = (i < N) ? deg[i] : 0;
    int val = v;
    sm[threadIdx.x] = val;
    __syncthreads();
    #pragma unroll
    for (int off = 1; off < SCAN_CHUNK; off <<= 1) {
        int t = (threadIdx.x >= off) ? sm[threadIdx.x - off] : 0;
        __syncthreads();
        val += t;
        sm[threadIdx.x] = val;
        __syncthreads();
    }
    if (i < N) offsets[i] = val - v;              // exclusive, block-local
    if (threadIdx.x == SCAN_CHUNK - 1) blockSums[blockIdx.x] = val;
}

// Single block: exclusive scan of blockSums in place (NB ~ 391, trivial serial)
__global__ void scan_block_kernel(int* __restrict__ blockSums, int NB) {
    if (threadIdx.x == 0 && blockIdx.x == 0) {
        int running = 0;
        for (int j = 0; j < NB; ++j) {
            int t = blockSums[j];
            blockSums[j] = running;
            running += t;
        }
    }
}

// Add block offsets; also snapshot into cursor for the fill pass
__global__ void scan_add_kernel(int* __restrict__ offsets, int* __restrict__ cursor,
                                const int* __restrict__ blockSums, int N) {
    int i = blockIdx.x * SCAN_CHUNK + threadIdx.x;
    if (i < N) {
        int o = offsets[i] + blockSums[blockIdx.x];
        offsets[i] = o;
        cursor[i]  = o;
    }
}

// Permute edges into dst-sorted order (src and val pre-gathered to kill double indirection)
__global__ void fill_kernel(const int* __restrict__ src, const int* __restrict__ dst,
                            const float* __restrict__ val, int* __restrict__ cursor,
                            int* __restrict__ src_s, float* __restrict__ val_s, int E) {
    int e = blockIdx.x * blockDim.x + threadIdx.x;
    if (e < E) {
        int p = atomicAdd(&cursor[dst[e]], 1);
        src_s[p] = src[e];
        val_s[p] = val[e];
    }
}

// ---------- fused gather + diag-w + LayerNorm (+ReLU) ----------
// One wave64 per node; float2 per lane covers D=128.
// acc = sum_e val_e * h[src_e]; then *w, LN, optional ReLU.
__global__ void gather_ln_kernel(const float* __restrict__ h,
                                 const int* __restrict__ offsets,
                                 const int* __restrict__ deg,
                                 const int* __restrict__ src_s,
                                 const float* __restrict__ val_s,
                                 const float* __restrict__ w,
                                 const float* __restrict__ g,
                                 const float* __restrict__ b,
                                 float* __restrict__ out,
                                 int N, int do_relu) {
    int node = blockIdx.x * (blockDim.x >> 6) + (threadIdx.x >> 6);
    int lane = threadIdx.x & 63;
    if (node >= N) return;

    int start = offsets[node];
    int cnt   = deg[node];

    float2 acc = make_float2(0.0f, 0.0f);
    for (int base = 0; base < cnt; base += 64) {
        int m = min(64, cnt - base);
        // cooperative coalesced load of up to 64 edges' metadata
        int s_l = 0; float v_l = 0.0f;
        if (lane < m) {
            s_l = src_s[start + base + lane];
            v_l = val_s[start + base + lane];
        }
        for (int j = 0; j < m; ++j) {
            int   s = __shfl(s_l, j, 64);
            float v = __shfl(v_l, j, 64);
            float2 hv = ((const float2*)(h + (size_t)s * D))[lane];
            acc.x = fmaf(v, hv.x, acc.x);
            acc.y = fmaf(v, hv.y, acc.y);
        }
    }

    // diagonal transform factors out of the sum
    float2 wv = ((const float2*)w)[lane];
    acc.x *= wv.x;
    acc.y *= wv.y;

    // LayerNorm over 128 features (wave shuffle reduction)
    float sum = acc.x + acc.y;
    #pragma unroll
    for (int off = 32; off > 0; off >>= 1) sum += __shfl_down(sum, off, 64);
    sum = __shfl(sum, 0, 64);
    float mu = sum * (1.0f / D);

    float dx = acc.x - mu, dy = acc.y - mu;
    float sq = dx * dx + dy * dy;
    #pragma unroll
    for (int off = 32; off > 0; off >>= 1) sq += __shfl_down(sq, off, 64);
    sq = __shfl(sq, 0, 64);
    float rstd = rsqrtf(sq * (1.0f / D) + LN_EPS);

    float2 gv = ((const float2*)g)[lane];
    float2 bv = ((const float2*)b)[lane];
    float2 o;
    o.x = dx * rstd * gv.x + bv.x;
    o.y = dy * rstd * gv.y + bv.y;
    if (do_relu) { o.x = fmaxf(o.x, 0.0f); o.y = fmaxf(o.y, 0.0f); }
    ((float2*)(out + (size_t)node * D))[lane] = o;
}

extern "C" void kernel_launch(void* const* d_in, const int* in_sizes, int n_in,
                              void* d_out, int out_size, void* d_ws, size_t ws_size,
                              hipStream_t stream) {
    const float* x    = (const float*)d_in[0];
    const int*   esrc = (const int*)d_in[1];
    const int*   edst = (const int*)d_in[2];
    const float* eval_= (const float*)d_in[3];
    const float* w1   = (const float*)d_in[4];
    const float* w2   = (const float*)d_in[5];
    const float* g1   = (const float*)d_in[6];
    const float* b1   = (const float*)d_in[7];
    const float* g2   = (const float*)d_in[8];
    const float* b2   = (const float*)d_in[9];
    float* out = (float*)d_out;

    const int N = in_sizes[0] / D;   // 100000
    const int E = in_sizes[1];       // 1600000
    const int NB = (N + SCAN_CHUNK - 1) / SCAN_CHUNK;

    // workspace layout (~65 MB)
    float* bufB    = (float*)d_ws;                       // N*D: layer-1 output
    int*   src_s   = (int*)(bufB + (size_t)N * D);       // E
    float* val_s   = (float*)(src_s + E);                // E
    int*   deg     = (int*)(val_s + E);                  // N
    int*   offsets = deg + N;                            // N
    int*   cursor  = offsets + N;                        // N
    int*   blockSums = cursor + N;                       // NB

    const int TB = 256;
    const int egrid = (E + TB - 1) / TB;
    const int ggrid = (N + 3) / 4;   // 4 waves/block, wave per node

    // ---- CSR build (edges identical for both layers; build once) ----
    hipMemsetAsync(deg, 0, (size_t)N * sizeof(int), stream);
    hist_kernel<<<egrid, TB, 0, stream>>>(edst, deg, E);
    scan_local_kernel<<<NB, SCAN_CHUNK, 0, stream>>>(deg, offsets, blockSums, N);
    scan_block_kernel<<<1, 64, 0, stream>>>(blockSums, NB);
    scan_add_kernel<<<NB, SCAN_CHUNK, 0, stream>>>(offsets, cursor, blockSums, N);
    fill_kernel<<<egrid, TB, 0, stream>>>(esrc, edst, eval_, cursor, src_s, val_s, E);

    // ---- layer 1: gather(x)*w1 -> LN -> ReLU -> bufB ----
    gather_ln_kernel<<<ggrid, TB, 0, stream>>>(x, offsets, deg, src_s, val_s,
                                               w1, g1, b1, bufB, N, 1);
    // ---- layer 2: gather(bufB)*w2 -> LN -> out ----
    gather_ln_kernel<<<ggrid, TB, 0, stream>>>(bufB, offsets, deg, src_s, val_s,
                                               w2, g2, b2, out, N, 0);
}

// Round 3
// 531.556 us; speedup vs baseline: 10.3597x; 1.1123x over previous
//
#include <hip/hip_runtime.h>

#define D 128
#define LN_EPS 1e-5f
#define SCAN_CHUNK 256

// ---- bf16 helpers (bf16 = upper 16 bits of f32; RNE pack) ----
__device__ inline float2 b2_to_f2(unsigned int u) {
    float2 r;
    r.x = __uint_as_float((u & 0xffffu) << 16);
    r.y = __uint_as_float(u & 0xffff0000u);
    return r;
}
__device__ inline unsigned int f2_to_b2(float2 v) {
    unsigned ux = __float_as_uint(v.x);
    unsigned uy = __float_as_uint(v.y);
    unsigned bx = (ux + 0x7fffu + ((ux >> 16) & 1u)) >> 16;
    unsigned by = (uy + 0x7fffu + ((uy >> 16) & 1u)) & 0xffff0000u;
    return bx | by;
}

// ---------- CSR build ----------

__global__ void hist_kernel(const int* __restrict__ dst, int* __restrict__ deg, int E) {
    int e = blockIdx.x * blockDim.x + threadIdx.x;
    if (e < E) atomicAdd(&deg[dst[e]], 1);
}

__global__ void scan_local_kernel(const int* __restrict__ deg, int* __restrict__ offsets,
                                  int* __restrict__ blockSums, int N) {
    __shared__ int sm[SCAN_CHUNK];
    int i = blockIdx.x * SCAN_CHUNK + threadIdx.x;
    int v = (i < N) ? deg[i] : 0;
    int val = v;
    sm[threadIdx.x] = val;
    __syncthreads();
    #pragma unroll
    for (int off = 1; off < SCAN_CHUNK; off <<= 1) {
        int t = (threadIdx.x >= off) ? sm[threadIdx.x - off] : 0;
        __syncthreads();
        val += t;
        sm[threadIdx.x] = val;
        __syncthreads();
    }
    if (i < N) offsets[i] = val - v;              // exclusive, block-local
    if (threadIdx.x == SCAN_CHUNK - 1) blockSums[blockIdx.x] = val;
}

// Parallel exclusive scan of blockSums (NB <= 512), one block
__global__ void scan_block_kernel(int* __restrict__ blockSums, int NB) {
    __shared__ int sm[512];
    int t = threadIdx.x;
    int v = (t < NB) ? blockSums[t] : 0;
    int val = v;
    sm[t] = val;
    __syncthreads();
    #pragma unroll
    for (int off = 1; off < 512; off <<= 1) {
        int tmp = (t >= off) ? sm[t - off] : 0;
        __syncthreads();
        val += tmp;
        sm[t] = val;
        __syncthreads();
    }
    if (t < NB) blockSums[t] = val - v;           // exclusive
}

__global__ void scan_add_kernel(int* __restrict__ offsets, int* __restrict__ cursor,
                                const int* __restrict__ blockSums, int N) {
    int i = blockIdx.x * SCAN_CHUNK + threadIdx.x;
    if (i < N) {
        int o = offsets[i] + blockSums[blockIdx.x];
        offsets[i] = o;
        cursor[i]  = o;
    }
}

// Permute edges into dst-sorted order; packed (src, val) single 8B store
__global__ void fill_kernel(const int* __restrict__ src, const int* __restrict__ dst,
                            const float* __restrict__ val, int* __restrict__ cursor,
                            uint2* __restrict__ edge_s, int E) {
    int e = blockIdx.x * blockDim.x + threadIdx.x;
    if (e < E) {
        int p = atomicAdd(&cursor[dst[e]], 1);
        edge_s[p] = make_uint2((unsigned)src[e], __float_as_uint(val[e]));
    }
}

// ---------- f32 -> packed bf16 conversion (for x) ----------
__global__ void f32_to_b2_kernel(const float* __restrict__ in,
                                 unsigned int* __restrict__ out, int n2) {
    int i = blockIdx.x * blockDim.x + threadIdx.x;
    if (i < n2) out[i] = f2_to_b2(((const float2*)in)[i]);
}

// ---------- fused gather + diag-w + LayerNorm (+ReLU) ----------
// One wave64/node; lane holds 2 features. h rows are packed bf16 (64 uints/row).
// mode 1: ReLU + write packed bf16 to out_b2. mode 0: write f32 to out_f32.
__global__ void gather_ln_kernel(const unsigned int* __restrict__ h2,
                                 const int* __restrict__ offsets,
                                 const int* __restrict__ deg,
                                 const uint2* __restrict__ edge_s,
                                 const float* __restrict__ w,
                                 const float* __restrict__ g,
                                 const float* __restrict__ b,
                                 float* __restrict__ out_f32,
                                 unsigned int* __restrict__ out_b2,
                                 int N, int mode) {
    int node = blockIdx.x * (blockDim.x >> 6) + (threadIdx.x >> 6);
    int lane = threadIdx.x & 63;
    if (node >= N) return;

    int start = offsets[node];
    int cnt   = deg[node];

    float2 acc = make_float2(0.0f, 0.0f);
    for (int base = 0; base < cnt; base += 64) {
        int m = min(64, cnt - base);
        uint2 e_l = make_uint2(0u, 0u);
        if (lane < m) e_l = edge_s[start + base + lane];
        for (int j = 0; j < m; ++j) {
            int   s = __shfl((int)e_l.x, j, 64);
            float v = __uint_as_float((unsigned)__shfl((int)e_l.y, j, 64));
            float2 hv = b2_to_f2(h2[(size_t)s * (D / 2) + lane]);
            acc.x = fmaf(v, hv.x, acc.x);
            acc.y = fmaf(v, hv.y, acc.y);
        }
    }

    float2 wv = ((const float2*)w)[lane];
    acc.x *= wv.x;
    acc.y *= wv.y;

    float sum = acc.x + acc.y;
    #pragma unroll
    for (int off = 32; off > 0; off >>= 1) sum += __shfl_down(sum, off, 64);
    sum = __shfl(sum, 0, 64);
    float mu = sum * (1.0f / D);

    float dx = acc.x - mu, dy = acc.y - mu;
    float sq = dx * dx + dy * dy;
    #pragma unroll
    for (int off = 32; off > 0; off >>= 1) sq += __shfl_down(sq, off, 64);
    sq = __shfl(sq, 0, 64);
    float rstd = rsqrtf(sq * (1.0f / D) + LN_EPS);

    float2 gv = ((const float2*)g)[lane];
    float2 bv = ((const float2*)b)[lane];
    float2 o;
    o.x = dx * rstd * gv.x + bv.x;
    o.y = dy * rstd * gv.y + bv.y;
    if (mode == 1) {
        o.x = fmaxf(o.x, 0.0f);
        o.y = fmaxf(o.y, 0.0f);
        out_b2[(size_t)node * (D / 2) + lane] = f2_to_b2(o);
    } else {
        ((float2*)(out_f32 + (size_t)node * D))[lane] = o;
    }
}

extern "C" void kernel_launch(void* const* d_in, const int* in_sizes, int n_in,
                              void* d_out, int out_size, void* d_ws, size_t ws_size,
                              hipStream_t stream) {
    const float* x    = (const float*)d_in[0];
    const int*   esrc = (const int*)d_in[1];
    const int*   edst = (const int*)d_in[2];
    const float* eval_= (const float*)d_in[3];
    const float* w1   = (const float*)d_in[4];
    const float* w2   = (const float*)d_in[5];
    const float* g1   = (const float*)d_in[6];
    const float* b1   = (const float*)d_in[7];
    const float* g2   = (const float*)d_in[8];
    const float* b2   = (const float*)d_in[9];
    float* out = (float*)d_out;

    const int N = in_sizes[0] / D;   // 100000
    const int E = in_sizes[1];       // 1600000
    const int NB = (N + SCAN_CHUNK - 1) / SCAN_CHUNK;   // 391

    // workspace layout
    unsigned int* xb      = (unsigned int*)d_ws;          // N*64 packed bf16 (25.6MB)
    unsigned int* hb      = xb + (size_t)N * (D / 2);     // N*64 packed bf16 (25.6MB)
    uint2*        edge_s  = (uint2*)(hb + (size_t)N * (D / 2)); // E uint2 (12.8MB)
    int*          deg     = (int*)(edge_s + E);           // N
    int*          offsets = deg + N;                      // N
    int*          cursor  = offsets + N;                  // N
    int*          blockSums = cursor + N;                 // NB

    const int TB = 256;
    const int egrid = (E + TB - 1) / TB;
    const int ggrid = (N + 3) / 4;               // 4 waves/block
    const int n2 = N * (D / 2);
    const int cgrid = (n2 + TB - 1) / TB;

    // ---- CSR build + x conversion ----
    hipMemsetAsync(deg, 0, (size_t)N * sizeof(int), stream);
    f32_to_b2_kernel<<<cgrid, TB, 0, stream>>>(x, xb, n2);
    hist_kernel<<<egrid, TB, 0, stream>>>(edst, deg, E);
    scan_local_kernel<<<NB, SCAN_CHUNK, 0, stream>>>(deg, offsets, blockSums, N);
    scan_block_kernel<<<1, 512, 0, stream>>>(blockSums, NB);
    scan_add_kernel<<<NB, SCAN_CHUNK, 0, stream>>>(offsets, cursor, blockSums, N);
    fill_kernel<<<egrid, TB, 0, stream>>>(esrc, edst, eval_, cursor, edge_s, E);

    // ---- layer 1: gather(xb)*w1 -> LN -> ReLU -> hb (bf16) ----
    gather_ln_kernel<<<ggrid, TB, 0, stream>>>(xb, offsets, deg, edge_s,
                                               w1, g1, b1, nullptr, hb, N, 1);
    // ---- layer 2: gather(hb)*w2 -> LN -> out (f32) ----
    gather_ln_kernel<<<ggrid, TB, 0, stream>>>(hb, offsets, deg, edge_s,
                                               w2, g2, b2, out, nullptr, N, 0);
}